// Round 5
// baseline (1917.118 us; speedup 1.0000x reference)
//
#include <hip/hip_runtime.h>

// DISCO block: conv(11x11, disk support) -> InstanceNorm -> LeakyReLU, twice.
// B=4, C=32, H=W=256. fp32 throughout (no fp32 MFMA on CDNA4 -> VALU conv).
//
// Structure: build dense kernels from the 36-basis expansion once, then
// direct conv with 89/121 disk-sparse taps. Weights AND input tile staged in
// LDS (weights as uniform ds_read_b128 broadcasts -> no reliance on compiler
// scalar-load promotion). Grid = 256 blocks = exactly 1 block/CU.
//
// [R4: no-change resubmission — 5x GPUAcquisitionTimeout. Holding audited
//  fp32 baseline; bf16-MFMA lever stays gated on a validated baseline
//  (wrong-kernel bench returns no counters -> blind debugging).]

#define HALO 5
#define TS   32            // output tile edge
#define TW   42            // TS + 2*HALO
#define TWP  43            // padded LDS row stride (odd -> worst 2-way bank alias, free)
#define ICC  4             // input channels per LDS chunk (tile+weights = 90.8 KB)

// ---------------------------------------------------------------------------
// Kernel-builder: PSI basis (fp64 math, matches numpy) and dense kernels in
// layout kern[ic][tap][oc] so the conv reads 32 contiguous floats per tap.
// ---------------------------------------------------------------------------
__global__ void build_kern_kernel(const float* __restrict__ w1,
                                  const float* __restrict__ w2,
                                  float* __restrict__ kern1,
                                  float* __restrict__ kern2) {
  __shared__ float psi[36 * 121];
  const int blk   = blockIdx.x;   // 0..63
  const int layer = blk >> 5;
  const int i     = blk & 31;
  const int tid   = threadIdx.x;  // 128 threads
  const double PI     = 3.141592653589793;
  const double TWO_PI = 6.283185307179586;
  for (int t = tid; t < 121; t += 128) {
    const int ky = t / 11, kx = t % 11;
    const double y = (ky - 5) / 255.0;
    const double x = (kx - 5) / 255.0;
    const double r = sqrt(x * x + y * y);
    double phi = atan2(y, x);
    if (phi < 0.0) phi += TWO_PI;
    const double inside = (r <= 0.02) ? 1.0 : 0.0;
    const double dr   = 0.02 / 5.0;
    const double dphi = TWO_PI / 7.0;
    psi[t] = (float)(fmax(0.0, 1.0 - r / dr) * inside);
    for (int j = 1; j < 6; ++j) {
      const double rad = fmax(0.0, 1.0 - fabs(r - j * dr) / dr) * inside;
      for (int k = 0; k < 7; ++k) {
        double d = fmod(phi - k * dphi + PI, TWO_PI);
        if (d < 0.0) d += TWO_PI;
        d = fabs(d - PI);
        const double ang = fmax(0.0, 1.0 - d / dphi);
        psi[(1 + (j - 1) * 7 + k) * 121 + t] = (float)(rad * ang);
      }
    }
  }
  __syncthreads();
  const float* w  = layer ? w2 : w1;
  float*       ko = (layer ? kern2 : kern1) + i * (121 * 32);
  for (int idx = tid; idx < 121 * 32; idx += 128) {
    const int t = idx >> 5;
    const int o = idx & 31;
    const float* wp = w + (o * 32 + i) * 36;  // w[o][i][k], K=36
    float s = 0.f;
#pragma unroll
    for (int k = 0; k < 36; ++k) s = fmaf(wp[k], psi[k * 121 + t], s);
    ko[t * 32 + o] = s;
  }
}

// ---------------------------------------------------------------------------
// Direct conv. Block: 32x32 output pixels, all 32 oc, one batch. 512 threads;
// thread owns 2 adjacent-x pixels x 32 oc (acc[64]). Per ICC=4 chunk, both
// the haloed input tile and the weight slab live in LDS. Both tap loops are
// compile-time -> the 32 zero taps outside the disk fold away.
// NORM_IN fuses the previous layer's InstanceNorm+LeakyReLU into staging.
// ---------------------------------------------------------------------------
template <bool NORM_IN>
__global__ __launch_bounds__(512, 2)
void conv_kernel(const float* __restrict__ in, const float* __restrict__ kern,
                 float* __restrict__ out, const float2* __restrict__ stats) {
  __shared__ float tile[ICC][TW * TWP];   // 4*42*43*4B = 28.9 KB
  __shared__ float wlds[ICC][121 * 32];   // 4*121*32*4B = 60.5 KB
  const int tid = threadIdx.x;
  const int txp = tid & 15;   // x-pair index -> x = 2*txp
  const int ty  = tid >> 4;   // 0..31
  const int bx0 = blockIdx.x * TS;
  const int by0 = blockIdx.y * TS;
  const int b   = blockIdx.z;

  float acc[64];
#pragma unroll
  for (int j = 0; j < 64; ++j) acc[j] = 0.f;

  for (int ic0 = 0; ic0 < 32; ic0 += ICC) {
    __syncthreads();
    // ---- stage ICC channels of the haloed tile ----
    for (int idx = tid; idx < ICC * TW * TW; idx += 512) {
      const int ci  = idx / (TW * TW);
      const int rem = idx - ci * (TW * TW);
      const int yy  = rem / TW;
      const int xx  = rem - yy * TW;
      const int gy  = by0 + yy - HALO;
      const int gx  = bx0 + xx - HALO;
      float v = 0.f;
      if ((unsigned)gy < 256u && (unsigned)gx < 256u) {
        v = in[(((b << 5) + ic0 + ci) << 16) + (gy << 8) + gx];
        if (NORM_IN) {
          const float2 st = stats[(b << 5) + ic0 + ci];
          v = (v - st.x) * st.y;
          v = v < 0.f ? 0.2f * v : v;
        }
      }
      tile[ci][yy * TWP + xx] = v;
    }
    // ---- stage ICC channels of weights (contiguous, float4-coalesced) ----
    {
      const float4* src =
          reinterpret_cast<const float4*>(kern + ic0 * (121 * 32));
      float4* dst = reinterpret_cast<float4*>(&wlds[0][0]);
      for (int idx = tid; idx < ICC * 121 * 8; idx += 512) dst[idx] = src[idx];
    }
    __syncthreads();
    // ---- accumulate ----
    for (int ci = 0; ci < ICC; ++ci) {
      const float* tb = &tile[ci][ty * TWP + 2 * txp];
      const float* wb = &wlds[ci][0];
#pragma unroll
      for (int kdy = 0; kdy < 11; ++kdy) {
#pragma unroll
        for (int kdx = 0; kdx < 11; ++kdx) {
          if ((kdy - 5) * (kdy - 5) + (kdx - 5) * (kdx - 5) > 26)
            continue;  // outside disk: kern==0 (folds at compile time)
          const float v0 = tb[kdy * TWP + kdx];
          const float v1 = tb[kdy * TWP + kdx + 1];
          const float4* kp =
              reinterpret_cast<const float4*>(wb + (kdy * 11 + kdx) * 32);
#pragma unroll
          for (int oq = 0; oq < 8; ++oq) {
            const float4 w = kp[oq];  // uniform addr -> broadcast ds_read_b128
            acc[8 * oq + 0] = fmaf(w.x, v0, acc[8 * oq + 0]);
            acc[8 * oq + 1] = fmaf(w.x, v1, acc[8 * oq + 1]);
            acc[8 * oq + 2] = fmaf(w.y, v0, acc[8 * oq + 2]);
            acc[8 * oq + 3] = fmaf(w.y, v1, acc[8 * oq + 3]);
            acc[8 * oq + 4] = fmaf(w.z, v0, acc[8 * oq + 4]);
            acc[8 * oq + 5] = fmaf(w.z, v1, acc[8 * oq + 5]);
            acc[8 * oq + 6] = fmaf(w.w, v0, acc[8 * oq + 6]);
            acc[8 * oq + 7] = fmaf(w.w, v1, acc[8 * oq + 7]);
          }
        }
      }
    }
  }
  // ---- write raw (pre-norm) conv output; o = 4*oq + c, acc[2*o], acc[2*o+1]
  const int gy = by0 + ty;
  const int gx = bx0 + 2 * txp;
#pragma unroll
  for (int o = 0; o < 32; ++o) {
    *reinterpret_cast<float2*>(&out[(((b << 5) + o) << 16) + (gy << 8) + gx]) =
        make_float2(acc[2 * o], acc[2 * o + 1]);
  }
}

// ---------------------------------------------------------------------------
// Per-(b,c) plane mean / rstd. One block per plane, no atomics.
// ---------------------------------------------------------------------------
__global__ void stats_kernel(const float* __restrict__ y,
                             float2* __restrict__ stats) {
  const int bo  = blockIdx.x;            // 0..127
  const int tid = threadIdx.x;           // 256 threads
  const float4* p = reinterpret_cast<const float4*>(y + (size_t)bo * 65536);
  float s = 0.f, q = 0.f;
  for (int i = tid; i < 16384; i += 256) {
    const float4 v = p[i];
    s += v.x + v.y + v.z + v.w;
    q += v.x * v.x + v.y * v.y + v.z * v.z + v.w * v.w;
  }
#pragma unroll
  for (int off = 32; off > 0; off >>= 1) {
    s += __shfl_down(s, off);
    q += __shfl_down(q, off);
  }
  __shared__ float sh[8];
  const int lane = tid & 63, wid = tid >> 6;
  if (lane == 0) { sh[wid] = s; sh[4 + wid] = q; }
  __syncthreads();
  if (tid == 0) {
    const float S = sh[0] + sh[1] + sh[2] + sh[3];
    const float Q = sh[4] + sh[5] + sh[6] + sh[7];
    const float mean = S * (1.f / 65536.f);
    const float var  = Q * (1.f / 65536.f) - mean * mean;
    stats[bo] = make_float2(mean, __frsqrt_rn(var + 1e-5f));
  }
}

// ---------------------------------------------------------------------------
// Final in-place InstanceNorm + LeakyReLU on d_out.
// ---------------------------------------------------------------------------
__global__ void finalize_kernel(float* __restrict__ y,
                                const float2* __restrict__ stats) {
  const int n4 = (4 * 32 * 65536) / 4;  // 2097152 float4s
  float4* p = reinterpret_cast<float4*>(y);
  for (int i = blockIdx.x * blockDim.x + threadIdx.x; i < n4;
       i += gridDim.x * blockDim.x) {
    float4 v = p[i];
    const float2 st = stats[i >> 14];   // 16384 float4 per plane
    float t;
    t = (v.x - st.x) * st.y; v.x = t < 0.f ? 0.2f * t : t;
    t = (v.y - st.x) * st.y; v.y = t < 0.f ? 0.2f * t : t;
    t = (v.z - st.x) * st.y; v.z = t < 0.f ? 0.2f * t : t;
    t = (v.w - st.x) * st.y; v.w = t < 0.f ? 0.2f * t : t;
    p[i] = v;
  }
}

// ---------------------------------------------------------------------------
extern "C" void kernel_launch(void* const* d_in, const int* in_sizes, int n_in,
                              void* d_out, int out_size, void* d_ws,
                              size_t ws_size, hipStream_t stream) {
  const float* image = (const float*)d_in[0];
  const float* w1    = (const float*)d_in[1];
  const float* w2    = (const float*)d_in[2];
  float* out = (float*)d_out;
  float* ws  = (float*)d_ws;

  // ws layout (floats): kern1[123904] kern2[123904] y1[8388608] stats[512]
  float*  kern1  = ws;
  float*  kern2  = ws + 123904;
  float*  y1     = ws + 247808;
  float2* stats1 = (float2*)(ws + 247808 + 8388608);
  float2* stats2 = stats1 + 128;

  build_kern_kernel<<<64, 128, 0, stream>>>(w1, w2, kern1, kern2);

  dim3 cgrid(8, 8, 4);  // W-tiles, H-tiles, batch
  conv_kernel<false><<<cgrid, 512, 0, stream>>>(image, kern1, y1, nullptr);
  stats_kernel<<<128, 256, 0, stream>>>(y1, stats1);
  conv_kernel<true><<<cgrid, 512, 0, stream>>>(y1, kern2, out, stats1);
  stats_kernel<<<128, 256, 0, stream>>>(out, stats2);
  finalize_kernel<<<2048, 256, 0, stream>>>(out, stats2);
}